// Round 1
// baseline (21.967 us; speedup 1.0000x reference)
//
#include <hip/hip_runtime.h>
#include <hip/hip_bf16.h>

// Problem constants (from reference):
//   B=32, S=512, D=768, N=128, LMAX=16
// Algebraic simplification:
//   softmax over l sums to 1 per column m (row 0 always valid since len>=1),
//   then columns are masked by valid[m], so
//   agg[b,n,d] = sum_{m=0}^{len-1} embeddings[b, start+m, d].
//   W and b cancel entirely.

constexpr int B_ = 32;
constexpr int S_ = 512;
constexpr int D_ = 768;
constexpr int N_ = 128;

__global__ __launch_bounds__(192) void span_sum_kernel(
    const float* __restrict__ emb,     // [B,S,D]
    const int*   __restrict__ spans,   // [B,N,2] (start, inclusive end)
    float*       __restrict__ out)     // [B,N,D]
{
    const int span_id = blockIdx.x;        // 0 .. B*N-1
    const int b = span_id / N_;
    const int t = threadIdx.x;             // 0..191 : float4 lane across D

    const int start = spans[2 * span_id + 0];
    const int end   = spans[2 * span_id + 1];   // inclusive
    const int len   = end - start + 1;          // 1..16, start+len <= S

    const float4* __restrict__ row =
        reinterpret_cast<const float4*>(emb + (size_t)b * S_ * D_ + (size_t)start * D_) + t;

    float4 acc = make_float4(0.f, 0.f, 0.f, 0.f);
    #pragma unroll 4
    for (int m = 0; m < len; ++m) {
        float4 v = row[(size_t)m * (D_ / 4)];
        acc.x += v.x; acc.y += v.y; acc.z += v.z; acc.w += v.w;
    }

    reinterpret_cast<float4*>(out + (size_t)span_id * D_)[t] = acc;
}

extern "C" void kernel_launch(void* const* d_in, const int* in_sizes, int n_in,
                              void* d_out, int out_size, void* d_ws, size_t ws_size,
                              hipStream_t stream) {
    const float* emb   = (const float*)d_in[0];   // [B,S,D] fp32
    // d_in[1] = W, d_in[2] = b : unused (cancel algebraically)
    const int*   spans = (const int*)d_in[3];     // [B,N,2] int32
    float*       out   = (float*)d_out;           // [B,N,D] fp32

    dim3 grid(B_ * N_);
    dim3 block(D_ / 4);  // 192 threads = 3 waves, one float4 per thread
    span_sum_kernel<<<grid, block, 0, stream>>>(emb, spans, out);
}

// Round 3
// 21.131 us; speedup vs baseline: 1.0396x; 1.0396x over previous
//
#include <hip/hip_runtime.h>
#include <hip/hip_bf16.h>

// Problem constants (from reference):
//   B=32, S=512, D=768, N=128, LMAX=16
// Algebraic simplification:
//   softmax over l sums to 1 per column m (row 0 always valid since len>=1),
//   then columns are masked by valid[m], so
//   agg[b,n,d] = sum_{m=0}^{len-1} embeddings[b, start+m, d].
//   W and b cancel entirely.
//
// R3: same as R2 (16 fully-unrolled independent loads, clamp+mask) but with
// a NATIVE clang vector type so __builtin_nontemporal_store compiles.

constexpr int B_ = 32;
constexpr int S_ = 512;
constexpr int D_ = 768;
constexpr int N_ = 128;
constexpr int LMAX_ = 16;

typedef float f32x4 __attribute__((ext_vector_type(4)));

__global__ __launch_bounds__(192) void span_sum_kernel(
    const float* __restrict__ emb,     // [B,S,D]
    const int*   __restrict__ spans,   // [B,N,2] (start, inclusive end)
    float*       __restrict__ out)     // [B,N,D]
{
    const int span_id = blockIdx.x;        // 0 .. B*N-1
    const int b = span_id / N_;
    const int t = threadIdx.x;             // 0..191 : float4 lane across D

    const int start = spans[2 * span_id + 0];   // uniform -> s_load
    const int end   = spans[2 * span_id + 1];   // inclusive
    const int lm1   = end - start;              // len-1, in [0,15]

    const f32x4* __restrict__ row =
        reinterpret_cast<const f32x4*>(emb + (size_t)b * S_ * D_ + (size_t)start * D_) + t;

    f32x4 acc = {0.f, 0.f, 0.f, 0.f};
    #pragma unroll
    for (int m = 0; m < LMAX_; ++m) {
        const int  mm = (m <= lm1) ? m : lm1;        // clamped row: always in-bounds
        const float s = (m <= lm1) ? 1.0f : 0.0f;    // mask
        f32x4 v = row[(size_t)mm * (D_ / 4)];        // 16 independent loads
        acc += s * v;
    }

    __builtin_nontemporal_store(acc, reinterpret_cast<f32x4*>(out + (size_t)span_id * D_) + t);
}

extern "C" void kernel_launch(void* const* d_in, const int* in_sizes, int n_in,
                              void* d_out, int out_size, void* d_ws, size_t ws_size,
                              hipStream_t stream) {
    const float* emb   = (const float*)d_in[0];   // [B,S,D] fp32
    // d_in[1] = W, d_in[2] = b : unused (cancel algebraically)
    const int*   spans = (const int*)d_in[3];     // [B,N,2] int32
    float*       out   = (float*)d_out;           // [B,N,D] fp32

    dim3 grid(B_ * N_);
    dim3 block(D_ / 4);  // 192 threads = 3 waves, one float4 per thread
    span_sum_kernel<<<grid, block, 0, stream>>>(emb, spans, out);
}

// Round 5
// 18.276 us; speedup vs baseline: 1.2020x; 1.1562x over previous
//
#include <hip/hip_runtime.h>
#include <hip/hip_bf16.h>

// Problem constants (from reference):
//   B=32, S=512, D=768, N=128, LMAX=16
// Algebraic simplification (verified R1: absmax 0.031 << 0.385):
//   softmax over l sums to 1 per column m (row 0 always valid since len>=1),
//   then columns are masked by valid[m], so
//   agg[b,n,d] = sum_{m=0}^{len-1} embeddings[b, start+m, d].
//   W and b cancel entirely.
//
// R5 changes vs R4:
//  1. PLAIN stores (no nontemporal). R4 failed post-timing revalidation:
//     harness poisons d_out through L2 (dirty lines); nt stores can be
//     overwritten by a later dirty-poison eviction -> timing-dependent
//     corruption. Plain stores share the poison's cache path.
//  2. LDS quad-rotation swizzle slot=(q+row)&7 on write AND read: compute
//     phase had each 8-lane group reading a full 128B row -> 8 row-addresses
//     per bank cluster (up to 8-way conflict). Rotation spreads groups.

constexpr int B_    = 32;
constexpr int S_    = 512;
constexpr int D_    = 768;
constexpr int N_    = 128;
constexpr int LMAX_ = 16;
constexpr int CHUNK  = 32;          // floats of D per block
constexpr int NCHUNK = D_ / CHUNK;  // 24
constexpr int QPC    = CHUNK / 4;   // 8 f32x4 quads per chunk

typedef float f32x4 __attribute__((ext_vector_type(4)));

__global__ __launch_bounds__(512) void span_sum_lds_kernel(
    const float* __restrict__ emb,     // [B,S,D]
    const int*   __restrict__ spans,   // [B,N,2] (start, inclusive end)
    float*       __restrict__ out)     // [B,N,D]
{
    __shared__ f32x4 lds[S_][QPC];     // 512 * 8 * 16B = 64 KiB

    const int blk = blockIdx.x;        // 0 .. B*NCHUNK-1
    const int b   = blk / NCHUNK;
    const int c   = blk % NCHUNK;
    const int t   = threadIdx.x;       // 0..511
    const int q   = t & (QPC - 1);     // quad within chunk, 0..7
    const int r0  = t >> 3;            // 0..63

    // ---- stage emb[b, :, c*32 .. c*32+31] into LDS (one HBM read) ----
    // swizzled slot: (q + row) & 7  (bijective per row)
    const float* src = emb + (size_t)b * S_ * D_ + (size_t)c * CHUNK;
    #pragma unroll
    for (int i = 0; i < S_ / 64; ++i) {          // 8 iters
        const int r = r0 + 64 * i;
        lds[r][(q + r) & (QPC - 1)] =
            *reinterpret_cast<const f32x4*>(src + (size_t)r * D_ + q * 4);
    }
    __syncthreads();

    // ---- all 128 spans of batch b from LDS ----
    #pragma unroll
    for (int j = 0; j < N_ / 64; ++j) {          // 2 iters
        const int span = r0 + 64 * j;            // 0..127
        const int sid  = b * N_ + span;
        const int start = spans[2 * sid + 0];
        const int lm1   = spans[2 * sid + 1] - start;   // len-1, 0..15

        f32x4 acc = {0.f, 0.f, 0.f, 0.f};
        #pragma unroll
        for (int m = 0; m < LMAX_; ++m) {
            const int  mm = start + ((m <= lm1) ? m : lm1);  // always in-bounds
            const float s = (m <= lm1) ? 1.0f : 0.0f;
            acc += s * lds[mm][(q + mm) & (QPC - 1)];        // swizzled read
        }
        *(reinterpret_cast<f32x4*>(out + (size_t)sid * D_ + c * CHUNK) + q) = acc;
    }
}

extern "C" void kernel_launch(void* const* d_in, const int* in_sizes, int n_in,
                              void* d_out, int out_size, void* d_ws, size_t ws_size,
                              hipStream_t stream) {
    const float* emb   = (const float*)d_in[0];   // [B,S,D] fp32
    // d_in[1] = W, d_in[2] = b : unused (cancel algebraically)
    const int*   spans = (const int*)d_in[3];     // [B,N,2] int32
    float*       out   = (float*)d_out;           // [B,N,D] fp32

    dim3 grid(B_ * NCHUNK);   // 768 blocks, 64KB LDS each -> 2 blocks/CU
    dim3 block(512);
    span_sum_lds_kernel<<<grid, block, 0, stream>>>(emb, spans, out);
}

// Round 6
// 15.448 us; speedup vs baseline: 1.4220x; 1.1831x over previous
//
#include <hip/hip_runtime.h>
#include <hip/hip_bf16.h>

// Problem constants (from reference):
//   B=32, S=512, D=768, N=128, LMAX=16
// Algebraic simplification (verified R1: absmax 0.031 << 0.385):
//   softmax over l sums to 1 per column m (row 0 always valid since len>=1),
//   then columns are masked by valid[m], so
//   agg[b,n,d] = sum_{m=0}^{len-1} embeddings[b, start+m, d].
//   W and b cancel entirely.
//
// R6: back to the direct per-span structure (contiguous 3KB row reads =
// good DRAM locality; R5's 128B@3KB-stride staging throttled HBM), plus an
// XCD-affinity swizzle so span-overlap re-reads hit the 4MB per-XCD L2:
//   bid -> xcd = bid&7, k = bid>>3, b = 4*xcd + k/128, n = k%128.
// Each XCD walks its 4 batches one at a time; 1.5MB batch working set stays
// L2-resident, converting ~56MB of HBM re-reads into L2 hits.
// Plain stores only (R4 lesson: nontemporal stores raced the harness's
// dirty poison lines in L2 -> post-timing corruption).

constexpr int B_    = 32;
constexpr int S_    = 512;
constexpr int D_    = 768;
constexpr int N_    = 128;
constexpr int LMAX_ = 16;

typedef float f32x4 __attribute__((ext_vector_type(4)));

__global__ __launch_bounds__(192) void span_sum_kernel(
    const float* __restrict__ emb,     // [B,S,D]
    const int*   __restrict__ spans,   // [B,N,2] (start, inclusive end)
    float*       __restrict__ out)     // [B,N,D]
{
    // XCD-affinity remap (bijective over 4096 blocks; dispatch round-robins
    // XCDs, so XCD x sees k=0,1,2,... i.e. batches 4x..4x+3 sequentially).
    const int bid = blockIdx.x;
    const int x   = bid & 7;           // XCD id (heuristic; perf-only)
    const int k   = bid >> 3;          // 0..511 within XCD
    const int b   = (x << 2) | (k >> 7);
    const int n   = k & (N_ - 1);
    const int sid = b * N_ + n;

    const int t = threadIdx.x;         // 0..191 : float4 lane across D

    const int start = spans[2 * sid + 0];
    const int end   = spans[2 * sid + 1];   // inclusive
    const int lm1   = end - start;          // len-1, in [0,15]

    const f32x4* __restrict__ row =
        reinterpret_cast<const f32x4*>(emb + (size_t)b * S_ * D_ + (size_t)start * D_) + t;

    f32x4 acc = {0.f, 0.f, 0.f, 0.f};
    #pragma unroll
    for (int m = 0; m < LMAX_; ++m) {
        const int  mm = (m <= lm1) ? m : lm1;        // clamped row: always in-bounds
        const float s = (m <= lm1) ? 1.0f : 0.0f;    // mask
        f32x4 v = row[(size_t)mm * (D_ / 4)];        // 16 independent loads
        acc += s * v;
    }

    *(reinterpret_cast<f32x4*>(out + (size_t)sid * D_) + t) = acc;
}

extern "C" void kernel_launch(void* const* d_in, const int* in_sizes, int n_in,
                              void* d_out, int out_size, void* d_ws, size_t ws_size,
                              hipStream_t stream) {
    const float* emb   = (const float*)d_in[0];   // [B,S,D] fp32
    // d_in[1] = W, d_in[2] = b : unused (cancel algebraically)
    const int*   spans = (const int*)d_in[3];     // [B,N,2] int32
    float*       out   = (float*)d_out;           // [B,N,D] fp32

    dim3 grid(B_ * N_);       // 4096 blocks
    dim3 block(D_ / 4);       // 192 threads = 3 waves
    span_sum_kernel<<<grid, block, 0, stream>>>(emb, spans, out);
}

// Round 7
// 15.185 us; speedup vs baseline: 1.4466x; 1.0173x over previous
//
#include <hip/hip_runtime.h>
#include <hip/hip_bf16.h>

// Problem constants (from reference):
//   B=32, S=512, D=768, N=128, LMAX=16
// Algebraic simplification (verified R1: absmax 0.031 << 0.385):
//   softmax over l sums to 1 per column m (row 0 always valid since len>=1),
//   then columns are masked by valid[m], so
//   agg[b,n,d] = sum_{m=0}^{len-1} embeddings[b, start+m, d].
//   W and b cancel entirely.
//
// R7 vs R6:
//  1. 4 spans/block (768 thr, 12 waves) -> 2 resident blocks/CU -> per-XCD
//     concurrent k-window ~64 blocks = 1-2 batches ~3MB working set, fits
//     the 4MB XCD L2 (R6's 320-block window spanned ~2.5 batches = 4.5MB,
//     thrashing). Grid 4096 -> 1024.
//  2. Group-of-4 load loop: skip whole groups past len (wave-uniform since
//     192 lanes = exactly 3 waves per span) -> wasted clamped loads <= 3
//     instead of ~7.5 avg, keeping 4-16 deep MLP.
// Plain stores only (R4 lesson: nt stores raced harness poison lines).

constexpr int B_    = 32;
constexpr int S_    = 512;
constexpr int D_    = 768;
constexpr int N_    = 128;
constexpr int LMAX_ = 16;
constexpr int SPB   = 4;            // spans per block
constexpr int TPS   = D_ / 4;       // 192 threads per span

typedef float f32x4 __attribute__((ext_vector_type(4)));

__global__ __launch_bounds__(SPB * TPS) void span_sum_kernel(
    const float* __restrict__ emb,     // [B,S,D]
    const int*   __restrict__ spans,   // [B,N,2] (start, inclusive end)
    float*       __restrict__ out)     // [B,N,D]
{
    // XCD-affinity remap: xcd = bid&7, k = bid>>3 (0..127);
    // batch = 4*xcd + k/32 (sequential per XCD), span group = k%32.
    const int bid = blockIdx.x;        // 0..1023
    const int x   = bid & 7;
    const int k   = bid >> 3;
    const int b   = (x << 2) | (k >> 5);
    const int g   = k & 31;

    const int t    = threadIdx.x;      // 0..767
    const int sp   = t / TPS;          // 0..3 (wave-aligned: 192 = 3 waves)
    const int lane = t - sp * TPS;     // 0..191 : f32x4 lane across D

    const int n   = (g << 2) | sp;
    const int sid = b * N_ + n;

    const int start = spans[2 * sid + 0];
    const int lm1   = spans[2 * sid + 1] - start;   // len-1, in [0,15]

    const f32x4* __restrict__ row =
        reinterpret_cast<const f32x4*>(emb + (size_t)b * S_ * D_ + (size_t)start * D_) + lane;

    f32x4 acc = {0.f, 0.f, 0.f, 0.f};
    #pragma unroll
    for (int gq = 0; gq < LMAX_ / 4; ++gq) {
        if ((gq << 2) <= lm1) {                      // wave-uniform branch
            #pragma unroll
            for (int m4 = 0; m4 < 4; ++m4) {
                const int  m  = (gq << 2) | m4;
                const int  mm = (m <= lm1) ? m : lm1;     // always in-bounds
                const float s = (m <= lm1) ? 1.0f : 0.0f; // mask
                acc += s * row[(size_t)mm * (D_ / 4)];
            }
        }
    }

    *(reinterpret_cast<f32x4*>(out + (size_t)sid * D_) + lane) = acc;
}

extern "C" void kernel_launch(void* const* d_in, const int* in_sizes, int n_in,
                              void* d_out, int out_size, void* d_ws, size_t ws_size,
                              hipStream_t stream) {
    const float* emb   = (const float*)d_in[0];   // [B,S,D] fp32
    // d_in[1] = W, d_in[2] = b : unused (cancel algebraically)
    const int*   spans = (const int*)d_in[3];     // [B,N,2] int32
    float*       out   = (float*)d_out;           // [B,N,D] fp32

    dim3 grid(B_ * N_ / SPB);     // 1024 blocks
    dim3 block(SPB * TPS);        // 768 threads = 12 waves
    span_sum_kernel<<<grid, block, 0, stream>>>(emb, spans, out);
}